// Round 1
// baseline (31459.540 us; speedup 1.0000x reference)
//
#include <hip/hip_runtime.h>

#define N_SEQ 2047
#define DIM   512
#define RANK  64
#define VOCAB 32000
#define SCALE 0.125f
#define LN_EPS 1e-5f

typedef __attribute__((ext_vector_type(4))) float  floatx4;
typedef __attribute__((ext_vector_type(8))) __bf16 bf16x8;
typedef __attribute__((ext_vector_type(4))) unsigned short ushortx4;

__device__ __forceinline__ unsigned short f2bf(float x) {
    unsigned int u = __builtin_bit_cast(unsigned int, x);
    return (unsigned short)((u + 0x7fffu + ((u >> 16) & 1u)) >> 16);
}

// ---------------------------------------------------------------- embedding
// s[n][:] = q[n][:] = E[ids[n+1]][:]
__global__ __launch_bounds__(128) void k_embed(const int* __restrict__ ids,
                                               const float* __restrict__ E,
                                               float* __restrict__ s,
                                               float* __restrict__ q) {
    int n = blockIdx.x;
    int id = ids[n + 1];
    float4 v = ((const float4*)(E + (size_t)id * DIM))[threadIdx.x];
    ((float4*)(s + (size_t)n * DIM))[threadIdx.x] = v;
    ((float4*)(q + (size_t)n * DIM))[threadIdx.x] = v;
}

// ---------------------------------------------------------------- copy M0 -> workspace
__global__ __launch_bounds__(128) void k_copyM(const float* __restrict__ m0,
                                               const float* __restrict__ m1,
                                               const float* __restrict__ m2,
                                               float* __restrict__ Mw) {
    int sl = blockIdx.x;
    const float* src = (sl < 256) ? (m0 + (size_t)sl * DIM)
                     : (sl < 320) ? (m1 + (size_t)(sl - 256) * DIM)
                                  : (m2 + (size_t)(sl - 320) * DIM);
    ((float4*)(Mw + (size_t)sl * DIM))[threadIdx.x] = ((const float4*)src)[threadIdx.x];
}

// ---------------------------------------------------------------- qr/xv projections
// qr[l][t][r] = s[t]·Ur[l][:,r]   xv[l][t][r] = s[t]·Vr[l][:,r]
__global__ __launch_bounds__(384) void k_proj(const float* __restrict__ s,
                                              const float* __restrict__ Ur,
                                              const float* __restrict__ Vr,
                                              float* __restrict__ qr,
                                              float* __restrict__ xv) {
    __shared__ float s8[8 * DIM];
    int t0 = blockIdx.x * 8;
    for (int i = threadIdx.x; i < 8 * DIM; i += 384) {
        int t = t0 + (i >> 9);
        s8[i] = (t < N_SEQ) ? s[(size_t)t * DIM + (i & 511)] : 0.f;
    }
    __syncthreads();
    int c = threadIdx.x;
    int l = (c % 192) / 64;
    int r = c & 63;
    const float* W = ((c < 192) ? Ur : Vr) + (size_t)l * DIM * RANK + r;
    float acc[8] = {};
    for (int d = 0; d < DIM; d++) {
        float w = W[(size_t)d * RANK];
        #pragma unroll
        for (int i = 0; i < 8; i++) acc[i] += s8[i * DIM + d] * w;
    }
    float* out = ((c < 192) ? qr : xv) + (size_t)l * N_SEQ * RANK;
    #pragma unroll
    for (int i = 0; i < 8; i++) {
        int t = t0 + i;
        if (t < N_SEQ) out[(size_t)t * RANK + r] = acc[i];
    }
}

// ---------------------------------------------------------------- kr0 = M0 @ Vr[l]
__global__ __launch_bounds__(64) void k_kr0(const float* __restrict__ m0,
                                            const float* __restrict__ m1,
                                            const float* __restrict__ m2,
                                            const float* __restrict__ Vr,
                                            float* __restrict__ kr) {
    __shared__ float mrow[DIM];
    int sl = blockIdx.x;
    int lvl = (sl < 256) ? 0 : (sl < 320 ? 1 : 2);
    const float* src = (lvl == 0) ? m0 + (size_t)sl * DIM
                     : (lvl == 1) ? m1 + (size_t)(sl - 256) * DIM
                                  : m2 + (size_t)(sl - 320) * DIM;
    for (int i = threadIdx.x; i < DIM / 4; i += 64)
        ((float4*)mrow)[i] = ((const float4*)src)[i];
    __syncthreads();
    const float* W = Vr + (size_t)lvl * DIM * RANK + threadIdx.x;
    float acc = 0.f;
    for (int d = 0; d < DIM; d++) acc += mrow[d] * W[(size_t)d * RANK];
    kr[(size_t)sl * RANK + threadIdx.x] = acc;
}

// ---------------------------------------------------------------- sequential memory scan
// one block per level; kr register-resident (thread==slot); M column-partitioned
__global__ __launch_bounds__(256) void k_scan(const float* __restrict__ s,
                                              const float* __restrict__ qr,
                                              const float* __restrict__ xv,
                                              float* __restrict__ Mw,
                                              const float* __restrict__ kr0,
                                              float* __restrict__ q) {
    __shared__ float qr_sw[4 * RANK];   // wave-private copies
    __shared__ float xv_sw[4 * RANK];
    __shared__ float scs[256];
    __shared__ float wsel_s[16];
    __shared__ int   isel_s[16];

    const int lvl   = blockIdx.x;
    const int S     = (lvl == 0) ? 256 : (lvl == 1 ? 64 : 16);
    const int imask = (lvl == 0) ? 0   : (lvl == 1 ? 3  : 15);
    const int base  = (lvl == 0) ? 0   : (lvl == 1 ? 256 : 320);
    const float* qrl = qr + (size_t)lvl * N_SEQ * RANK;
    const float* xvl = xv + (size_t)lvl * N_SEQ * RANK;
    float* Ml        = Mw + (size_t)base * DIM;
    const float* krl = kr0 + (size_t)base * RANK;

    const int tid  = threadIdx.x;
    const int lane = tid & 63;
    const int wb   = (tid >> 6) * RANK;
    const int d0   = tid * 2;

    float krr[RANK];
    if (tid < S) {
        #pragma unroll
        for (int i = 0; i < RANK / 4; i++)
            ((floatx4*)krr)[i] = ((const floatx4*)(krl + (size_t)tid * RANK))[i];
    } else {
        #pragma unroll
        for (int r = 0; r < RANK; r++) krr[r] = 0.f;
    }

    for (int t = 0; t < N_SEQ; t++) {
        const int gate = ((t & imask) == 0);
        // stage qr_t (and xv_t on gate steps) wave-privately: no barrier needed
        qr_sw[wb + lane] = qrl[(size_t)t * RANK + lane];
        if (gate) xv_sw[wb + lane] = xvl[(size_t)t * RANK + lane];
        // scores: sc[slot] = scale * qr_t . kr[slot]
        float acc = 0.f;
        #pragma unroll
        for (int r = 0; r < RANK; r++) acc += qr_sw[wb + r] * krr[r];
        if (tid < S) scs[tid] = acc * SCALE;
        __syncthreads();                               // B2
        float myval = 0.f; int myslot = 0;
        if (tid < 64) {
            float cv0 = (tid       < S) ? scs[tid]       : -3.0e38f;
            float cv1 = (tid + 64  < S) ? scs[tid + 64]  : -3.0e38f;
            float cv2 = (tid + 128 < S) ? scs[tid + 128] : -3.0e38f;
            float cv3 = (tid + 192 < S) ? scs[tid + 192] : -3.0e38f;
            #pragma unroll 1
            for (int k = 0; k < 16; k++) {
                float bv = cv0; int bj = 0;
                if (cv1 > bv) { bv = cv1; bj = 1; }
                if (cv2 > bv) { bv = cv2; bj = 2; }
                if (cv3 > bv) { bv = cv3; bj = 3; }
                int bs = tid + (bj << 6);
                #pragma unroll
                for (int off = 1; off < 64; off <<= 1) {
                    float ov = __shfl_xor(bv, off, 64);
                    int   os = __shfl_xor(bs, off, 64);
                    if (ov > bv || (ov == bv && os < bs)) { bv = ov; bs = os; }
                }
                if ((bs & 63) == tid) {          // owner masks out the winner
                    int j = bs >> 6;
                    if      (j == 0) cv0 = -3.0e38f;
                    else if (j == 1) cv1 = -3.0e38f;
                    else if (j == 2) cv2 = -3.0e38f;
                    else             cv3 = -3.0e38f;
                }
                if (tid == k) { myval = bv; myslot = bs; }
            }
            if (tid < 16) {                      // softmax over the 16 (desc-sorted) vals
                float mx = __shfl(myval, 0, 64);
                float e = expf(myval - mx);
                float sum = e;
                #pragma unroll
                for (int off = 8; off >= 1; off >>= 1) sum += __shfl_xor(sum, off, 16);
                wsel_s[tid] = e / sum;
                isel_s[tid] = myslot;
            }
        }
        __syncthreads();                               // B3
        // read contribution from PRE-update M; each thread owns cols d0,d0+1
        float c0 = 0.f, c1 = 0.f;
        #pragma unroll
        for (int k = 0; k < 16; k++) {
            const float wk = wsel_s[k];
            const float* Mr = Ml + (size_t)isel_s[k] * DIM + d0;
            c0 += wk * Mr[0];
            c1 += wk * Mr[1];
        }
        atomicAdd(&q[(size_t)t * DIM + d0],     c0);
        atomicAdd(&q[(size_t)t * DIM + d0 + 1], c1);
        if (gate) {
            const float s0 = s[(size_t)t * DIM + d0];
            const float s1 = s[(size_t)t * DIM + d0 + 1];
            #pragma unroll
            for (int k = 0; k < 16; k++) {
                const float wk = wsel_s[k];
                float* Mr = Ml + (size_t)isel_s[k] * DIM + d0;
                Mr[0] += wk * s0;
                Mr[1] += wk * s1;
            }
            if (tid < S) {                       // incremental kr update (register)
                float wloc = 0.f;
                #pragma unroll
                for (int k = 0; k < 16; k++)
                    if (isel_s[k] == tid) wloc = wsel_s[k];
                if (wloc != 0.f) {
                    #pragma unroll
                    for (int r = 0; r < RANK; r++) krr[r] += wloc * xv_sw[wb + r];
                }
            }
        }
    }
}

// ---------------------------------------------------------------- h = LN(q @ Wproj^T)
__global__ __launch_bounds__(256) void k_wproj_ln(const float* __restrict__ q,
                                                  const float* __restrict__ Wp,
                                                  const float* __restrict__ g,
                                                  const float* __restrict__ b,
                                                  float* __restrict__ h) {
    __shared__ float q8[8 * DIM];
    __shared__ float hp[8 * DIM];
    int t0 = blockIdx.x * 8;
    for (int i = threadIdx.x; i < 8 * DIM; i += 256) {
        int t = t0 + (i >> 9);
        q8[i] = (t < N_SEQ) ? q[(size_t)t * DIM + (i & 511)] : 0.f;
    }
    __syncthreads();
    int c0 = threadIdx.x * 2;
    float acc0[8] = {}, acc1[8] = {};
    const float* w0 = Wp + (size_t)c0 * DIM;
    const float* w1 = w0 + DIM;
    for (int d = 0; d < DIM; d++) {
        float a0 = w0[d], a1 = w1[d];
        #pragma unroll
        for (int i = 0; i < 8; i++) {
            float qv = q8[i * DIM + d];
            acc0[i] += qv * a0;
            acc1[i] += qv * a1;
        }
    }
    #pragma unroll
    for (int i = 0; i < 8; i++) {
        hp[i * DIM + c0]     = acc0[i];
        hp[i * DIM + c0 + 1] = acc1[i];
    }
    __syncthreads();
    int rowi = threadIdx.x >> 5;
    int l32  = threadIdx.x & 31;
    int t = t0 + rowi;
    if (t < N_SEQ) {
        float sum = 0.f, sq = 0.f;
        #pragma unroll
        for (int u = 0; u < 16; u++) {
            float x = hp[rowi * DIM + l32 + u * 32];
            sum += x; sq += x * x;
        }
        #pragma unroll
        for (int off = 16; off >= 1; off >>= 1) {
            sum += __shfl_xor(sum, off, 32);
            sq  += __shfl_xor(sq,  off, 32);
        }
        float mean = sum * (1.f / DIM);
        float var  = sq * (1.f / DIM) - mean * mean;
        float inv  = rsqrtf(var + LN_EPS);
        #pragma unroll
        for (int u = 0; u < 16; u++) {
            int d = l32 + u * 32;
            float x = hp[rowi * DIM + d];
            h[(size_t)t * DIM + d] = (x - mean) * inv * g[d] + b[d];
        }
    }
}

// ---------------------------------------------------------------- a = h@Wq, kf = h@Wk
__global__ __launch_bounds__(128) void k_qk(const float* __restrict__ h,
                                            const float* __restrict__ Wq,
                                            const float* __restrict__ Wk,
                                            float* __restrict__ a,
                                            float* __restrict__ kf) {
    __shared__ float h8[8 * DIM];
    int t0 = blockIdx.x * 8;
    for (int i = threadIdx.x; i < 8 * DIM; i += 128) {
        int t = t0 + (i >> 9);
        h8[i] = (t < N_SEQ) ? h[(size_t)t * DIM + (i & 511)] : 0.f;
    }
    __syncthreads();
    int c = threadIdx.x;
    int r = c & 63;
    const float* W = ((c < 64) ? Wq : Wk) + r;
    float acc[8] = {};
    for (int d = 0; d < DIM; d++) {
        float w = W[(size_t)d * RANK];
        #pragma unroll
        for (int i = 0; i < 8; i++) acc[i] += h8[i * DIM + d] * w;
    }
    float* out = (c < 64) ? a : kf;
    #pragma unroll
    for (int i = 0; i < 8; i++) {
        int t = t0 + i;
        if (t < N_SEQ) out[(size_t)t * RANK + r] = acc[i];
    }
}

// ---------------------------------------------------------------- signed sliding-window attention + LN
__global__ __launch_bounds__(64) void k_attn(const float* __restrict__ hin,
                                             const float* __restrict__ a,
                                             const float* __restrict__ kf,
                                             const float* __restrict__ g,
                                             const float* __restrict__ b,
                                             float* __restrict__ hout) {
    __shared__ float a_s[64];
    __shared__ float w_s[64];
    int t = blockIdx.x;
    int lane = threadIdx.x;
    a_s[lane] = a[(size_t)t * RANK + lane];
    __syncthreads();
    int src  = t - 63 + lane;
    int srcc = src < 0 ? 0 : src;
    const float* kr_ = kf + (size_t)srcc * RANK;
    float sc = 0.f;
    #pragma unroll 8
    for (int r = 0; r < RANK; r++) sc += a_s[r] * kr_[r];
    sc *= SCALE;
    float logit = (src >= 0) ? fabsf(sc) : -1e9f;
    float m = logit;
    #pragma unroll
    for (int off = 32; off >= 1; off >>= 1) m = fmaxf(m, __shfl_xor(m, off, 64));
    float e = expf(logit - m);
    float sum = e;
    #pragma unroll
    for (int off = 32; off >= 1; off >>= 1) sum += __shfl_xor(sum, off, 64);
    float sgn = (sc > 0.f) ? 1.f : ((sc < 0.f) ? -1.f : 0.f);
    float w = (src >= 0) ? (e / sum) * sgn : 0.f;
    w_s[lane] = w;
    __syncthreads();
    float acc[8] = {};
    int basej = t - 63;
    for (int j = 0; j < 64; j++) {
        float wj = w_s[j];
        int sj = basej + j; sj = sj < 0 ? 0 : sj;
        const float* hr = hin + (size_t)sj * DIM + lane;
        #pragma unroll
        for (int u = 0; u < 8; u++) acc[u] += wj * hr[u * 64];
    }
    const float* hrow = hin + (size_t)t * DIM + lane;
    float x[8]; float sum2 = 0.f, sq = 0.f;
    #pragma unroll
    for (int u = 0; u < 8; u++) {
        x[u] = hrow[u * 64] + acc[u];
        sum2 += x[u]; sq += x[u] * x[u];
    }
    #pragma unroll
    for (int off = 32; off >= 1; off >>= 1) {
        sum2 += __shfl_xor(sum2, off, 64);
        sq   += __shfl_xor(sq,   off, 64);
    }
    float mean = sum2 * (1.f / DIM);
    float var  = sq * (1.f / DIM) - mean * mean;
    float inv  = rsqrtf(var + LN_EPS);
    #pragma unroll
    for (int u = 0; u < 8; u++) {
        int d = lane + u * 64;
        hout[(size_t)t * DIM + d] = (x[u] - mean) * inv * g[d] + b[d];
    }
}

// ---------------------------------------------------------------- final LN into padded (2048,512) buffer
__global__ __launch_bounds__(64) void k_ln_out(const float* __restrict__ hin,
                                               const float* __restrict__ g,
                                               const float* __restrict__ b,
                                               float* __restrict__ hP) {
    int t = blockIdx.x;
    int lane = threadIdx.x;
    if (t >= N_SEQ) {
        #pragma unroll
        for (int u = 0; u < 8; u++) hP[(size_t)t * DIM + lane + u * 64] = 0.f;
        return;
    }
    const float* hrow = hin + (size_t)t * DIM + lane;
    float x[8]; float sum = 0.f, sq = 0.f;
    #pragma unroll
    for (int u = 0; u < 8; u++) {
        x[u] = hrow[u * 64];
        sum += x[u]; sq += x[u] * x[u];
    }
    #pragma unroll
    for (int off = 32; off >= 1; off >>= 1) {
        sum += __shfl_xor(sum, off, 64);
        sq  += __shfl_xor(sq,  off, 64);
    }
    float mean = sum * (1.f / DIM);
    float var  = sq * (1.f / DIM) - mean * mean;
    float inv  = rsqrtf(var + LN_EPS);
    #pragma unroll
    for (int u = 0; u < 8; u++) {
        int d = lane + u * 64;
        hP[(size_t)t * DIM + d] = (x[u] - mean) * inv * g[d] + b[d];
    }
}

// ---------------------------------------------------------------- logits = A(2048,512) @ E^T(512,32000), bf16 MFMA
__global__ __launch_bounds__(256) void k_gemm(const float* __restrict__ A,
                                              const float* __restrict__ E,
                                              float* __restrict__ C) {
    __shared__ unsigned short As[128 * 64];
    __shared__ unsigned short Bs[128 * 64];
    int bm = blockIdx.y, bn = blockIdx.x;
    int tid = threadIdx.x;
    int lane = tid & 63, wave = tid >> 6;
    int wm = (wave >> 1) << 6, wn = (wave & 1) << 6;
    floatx4 acc[4][4] = {};
    for (int k0 = 0; k0 < DIM; k0 += 64) {
        #pragma unroll
        for (int ch = 0; ch < 8; ch++) {
            int f4 = ch * 256 + tid;
            int el = f4 * 4;
            int row = el >> 6;
            int kk = el & 63;
            int csw = (kk >> 3) ^ (row & 7);          // xor-swizzle 16B chunks
            int dst = row * 64 + csw * 8 + (kk & 7);
            float4 av = *(const float4*)(A + (size_t)(bm * 128 + row) * DIM + k0 + kk);
            ushortx4 ua = { f2bf(av.x), f2bf(av.y), f2bf(av.z), f2bf(av.w) };
            *(ushortx4*)&As[dst] = ua;
            float4 bv = *(const float4*)(E + (size_t)(bn * 128 + row) * DIM + k0 + kk);
            ushortx4 ub = { f2bf(bv.x), f2bf(bv.y), f2bf(bv.z), f2bf(bv.w) };
            *(ushortx4*)&Bs[dst] = ub;
        }
        __syncthreads();
        int mr = lane & 15, qd = lane >> 4;
        #pragma unroll
        for (int kh = 0; kh < 2; kh++) {
            bf16x8 af[4], bfr[4];
            #pragma unroll
            for (int i = 0; i < 4; i++) {
                int row = wm + i * 16 + mr;
                int c = kh * 4 + qd;
                af[i] = *(const bf16x8*)&As[row * 64 + ((c ^ (row & 7)) << 3)];
            }
            #pragma unroll
            for (int j = 0; j < 4; j++) {
                int row = wn + j * 16 + mr;
                int c = kh * 4 + qd;
                bfr[j] = *(const bf16x8*)&Bs[row * 64 + ((c ^ (row & 7)) << 3)];
            }
            #pragma unroll
            for (int i = 0; i < 4; i++)
                #pragma unroll
                for (int j = 0; j < 4; j++)
                    acc[i][j] = __builtin_amdgcn_mfma_f32_16x16x32_bf16(af[i], bfr[j], acc[i][j], 0, 0, 0);
        }
        __syncthreads();
    }
    int lr = lane >> 4, lc = lane & 15;
    #pragma unroll
    for (int i = 0; i < 4; i++)
        #pragma unroll
        for (int j = 0; j < 4; j++)
            #pragma unroll
            for (int reg = 0; reg < 4; reg++) {
                int gr = bm * 128 + wm + i * 16 + lr * 4 + reg;
                int gc = bn * 128 + wn + j * 16 + lc;
                if (gr < N_SEQ) C[(size_t)gr * VOCAB + gc] = acc[i][j][reg];
            }
}

// ----------------------------------------------------------------
extern "C" void kernel_launch(void* const* d_in, const int* in_sizes, int n_in,
                              void* d_out, int out_size, void* d_ws, size_t ws_size,
                              hipStream_t stream) {
    (void)in_sizes; (void)n_in; (void)out_size; (void)ws_size;
    const int*   ids  = (const int*)d_in[0];
    const float* E    = (const float*)d_in[1];
    const float* Ur   = (const float*)d_in[2];
    const float* Vr   = (const float*)d_in[3];
    const float* m0   = (const float*)d_in[4];
    const float* m1   = (const float*)d_in[5];
    const float* m2   = (const float*)d_in[6];
    const float* Wp   = (const float*)d_in[7];
    const float* Wq   = (const float*)d_in[8];
    const float* Wk   = (const float*)d_in[9];
    const float* lig  = (const float*)d_in[10];
    const float* lib  = (const float*)d_in[11];
    const float* lpg  = (const float*)d_in[12];
    const float* lpb  = (const float*)d_in[13];
    const float* log_ = (const float*)d_in[14];
    const float* lob  = (const float*)d_in[15];
    float* out = (float*)d_out;

    float* ws = (float*)d_ws;
    size_t off = 0;
    auto alloc = [&](size_t n) { float* p = ws + off; off += (n + 255) & ~(size_t)255; return p; };
    float* s   = alloc((size_t)N_SEQ * DIM);
    float* q   = alloc((size_t)N_SEQ * DIM);
    float* qr  = alloc((size_t)3 * N_SEQ * RANK);
    float* xv  = alloc((size_t)3 * N_SEQ * RANK);
    float* Mw  = alloc((size_t)336 * DIM);
    float* kr  = alloc((size_t)336 * RANK);
    float* hA  = alloc((size_t)N_SEQ * DIM);
    float* hB  = alloc((size_t)N_SEQ * DIM);
    float* ab  = alloc((size_t)N_SEQ * RANK);
    float* kfb = alloc((size_t)N_SEQ * RANK);
    float* hP  = alloc((size_t)2048 * DIM);

    k_embed   <<<N_SEQ, 128, 0, stream>>>(ids, E, s, q);
    k_copyM   <<<336, 128, 0, stream>>>(m0, m1, m2, Mw);
    k_proj    <<<256, 384, 0, stream>>>(s, Ur, Vr, qr, xv);
    k_kr0     <<<336, 64, 0, stream>>>(m0, m1, m2, Vr, kr);
    k_scan    <<<3, 256, 0, stream>>>(s, qr, xv, Mw, kr, q);
    k_wproj_ln<<<256, 256, 0, stream>>>(q, Wp, lig, lib, hA);
    k_qk      <<<256, 128, 0, stream>>>(hA, Wq, Wk, ab, kfb);
    k_attn    <<<N_SEQ, 64, 0, stream>>>(hA, ab, kfb, lpg, lpb, hB);
    k_qk      <<<256, 128, 0, stream>>>(hB, Wq + DIM * RANK, Wk + DIM * RANK, ab, kfb);
    k_attn    <<<N_SEQ, 64, 0, stream>>>(hB, ab, kfb, lpg + DIM, lpb + DIM, hA);
    k_ln_out  <<<2048, 64, 0, stream>>>(hA, log_, lob, hP);
    dim3 gg(VOCAB / 128, 2048 / 128);
    k_gemm    <<<gg, 256, 0, stream>>>(hP, E, out);
}